// Round 13
// baseline (174.162 us; speedup 1.0000x reference)
//
#include <hip/hip_runtime.h>

#define NPTS 4096
#define NB   8
#define BN_EPS 1e-5f
#define LOG2E 1.4426950408889634f
#define RS_SLICES 8   // m-slices in row-sum pass (k2)
#define CS_SLICES 4   // n-slices in column pass (k4)

typedef float f32x16 __attribute__((ext_vector_type(16)));
typedef short bf16x8 __attribute__((ext_vector_type(8)));
typedef unsigned short ushort_t;

#if __has_builtin(__builtin_amdgcn_exp2f)
#define EXP2(x) __builtin_amdgcn_exp2f(x)
#else
#define EXP2(x) exp2f(x)
#endif

__device__ __forceinline__ ushort_t f2bf(float f) {
    unsigned u = __builtin_bit_cast(unsigned, f);
    unsigned r = (u + 0x7FFFu + ((u >> 16) & 1u)) >> 16;
    return (ushort_t)r;
}

// ---------------- k0: fold BN + combine head weights with w2 ----------------
__global__ __launch_bounds__(256) void k0_prep(
    const float* __restrict__ w1, const float* __restrict__ g1, const float* __restrict__ b1,
    const float* __restrict__ m1, const float* __restrict__ v1,
    const float* __restrict__ w2,
    const float* __restrict__ wq, const float* __restrict__ gq, const float* __restrict__ bq,
    const float* __restrict__ mq, const float* __restrict__ vq,
    const float* __restrict__ wk, const float* __restrict__ gk, const float* __restrict__ bk,
    const float* __restrict__ mk, const float* __restrict__ vk,
    const float* __restrict__ wv, const float* __restrict__ gv, const float* __restrict__ bv,
    const float* __restrict__ mv, const float* __restrict__ vv,
    float* __restrict__ Wc, float* __restrict__ tb,
    float* __restrict__ w1s, float* __restrict__ t1)
{
    const int j = blockIdx.x;
    const int t = threadIdx.x;
    if (j == 35) {
        if (t < 64) {
            float s = g1[t] * rsqrtf(v1[t] + BN_EPS);
            w1s[t*3+0] = s * w1[t*3+0];
            w1s[t*3+1] = s * w1[t*3+1];
            w1s[t*3+2] = s * w1[t*3+2];
            t1[t] = b1[t] - s * m1[t];
        }
        return;
    }
    __shared__ float red[256];
    const int c = t & 63;
    const int chunk = t >> 6;
    const float* wrow;
    float g, bb, mm, vr, post = 1.f;
    if (j < 16)      { wrow = wq + j*128;      g = gq[j];    bb = bq[j];    mm = mq[j];    vr = vq[j];    post = LOG2E; }
    else if (j < 32) { int u = j-16; wrow = wk + u*128; g = gk[u]; bb = bk[u]; mm = mk[u]; vr = vk[u]; }
    else             { int u = j-32; wrow = wv + u*128; g = gv[u]; bb = bv[u]; mm = mv[u]; vr = vv[u]; }
    float acc = 0.f;
    for (int o = chunk*32; o < chunk*32 + 32; ++o) acc = fmaf(wrow[o], w2[o*64 + c], acc);
    red[t] = acc;
    __syncthreads();
    if (t < 64) {
        const float s4 = red[t] + red[64+t] + red[128+t] + red[192+t];
        const float sbn = g * rsqrtf(vr + BN_EPS);
        Wc[j*64 + t] = post * sbn * s4;
        if (t == 0) tb[j] = post * (bb - sbn * mm);
    }
}

// ---------------- k1: MLP, 4 threads per point ----------------
// grid 512 x 256: thread group of 4 handles one point, each 16 hidden chans.
__global__ __launch_bounds__(256) void k1_mlp(
    const float* __restrict__ x, const float* __restrict__ offset,
    const float* __restrict__ Wc, const float* __restrict__ tb,
    const float* __restrict__ w1s, const float* __restrict__ t1,
    ushort_t* __restrict__ qbuf, ushort_t* __restrict__ kbuf, float* __restrict__ aux)
{
    const int gt = blockIdx.x*256 + threadIdx.x;   // 0..131071
    const int p = gt >> 2;                          // point 0..32767
    const int sub = gt & 3;
    const int b = p >> 12;
    const int n = p & 4095;
    const float off = offset[0];
    const float* xb = x + (size_t)b*3*NPTS + n;
    const float x0 = xb[0] + off, x1 = xb[NPTS] + off, x2 = xb[2*NPTS] + off;

    float acc[35];
    if (sub == 0) {
#pragma unroll
        for (int j = 0; j < 35; ++j) acc[j] = tb[j];
    } else {
#pragma unroll
        for (int j = 0; j < 35; ++j) acc[j] = 0.f;
    }

    const int c0 = sub * 16;
#pragma unroll
    for (int ci = 0; ci < 16; ++ci) {
        const int c = c0 + ci;
        const float h = fmaxf(
            fmaf(w1s[c*3+0], x0, fmaf(w1s[c*3+1], x1, fmaf(w1s[c*3+2], x2, t1[c]))), 0.f);
        const float* wc = Wc + c;
#pragma unroll
        for (int j = 0; j < 35; ++j) acc[j] = fmaf(wc[j*64], h, acc[j]);
    }

    // reduce across the 4-lane group
#pragma unroll
    for (int j = 0; j < 35; ++j) {
        acc[j] += __shfl_xor(acc[j], 1);
        acc[j] += __shfl_xor(acc[j], 2);
    }

    if (sub == 0) {
        unsigned qw[8], kw[8];
#pragma unroll
        for (int i = 0; i < 8; ++i) {
            ushort_t qlo = f2bf(fmaxf(acc[2*i],    0.f));
            ushort_t qhi = f2bf(fmaxf(acc[2*i+1],  0.f));
            qw[i] = (unsigned)qlo | ((unsigned)qhi << 16);
            ushort_t klo = f2bf(fmaxf(acc[16+2*i],   0.f));
            ushort_t khi = f2bf(fmaxf(acc[16+2*i+1], 0.f));
            kw[i] = (unsigned)klo | ((unsigned)khi << 16);
        }
        uint4* qd = (uint4*)(qbuf + (size_t)p*16);
        qd[0] = make_uint4(qw[0], qw[1], qw[2], qw[3]);
        qd[1] = make_uint4(qw[4], qw[5], qw[6], qw[7]);
        uint4* kd = (uint4*)(kbuf + (size_t)p*16);
        kd[0] = make_uint4(kw[0], kw[1], kw[2], kw[3]);
        kd[1] = make_uint4(kw[4], kw[5], kw[6], kw[7]);
        float4* ar = (float4*)(aux + (size_t)p*4);
        *ar = make_float4(fmaxf(acc[32], 0.f), fmaxf(acc[33], 0.f), fmaxf(acc[34], 0.f), 0.f);
    }
}

// ---------------- k2: row sums via 32x32x16 MFMA, 8 m-slices, prefetch-2 ----
__global__ __launch_bounds__(256, 8) void k2_rowsum(
    const ushort_t* __restrict__ qbuf, const ushort_t* __restrict__ kbuf,
    float* __restrict__ psum)
{
    const int lane = threadIdx.x & 63;
    const int w = blockIdx.x*4 + (threadIdx.x >> 6);
    const int b = w >> 10;
    const int r = w & 1023;
    const int nblk = r >> 3;
    const int slice = r & 7;
    const int n0 = nblk * 32;
    const int m0 = slice * 512;

    const bf16x8 qfrag = *(const bf16x8*)(qbuf + ((size_t)b*NPTS + n0 + (lane & 31))*16 + (lane >> 5)*8);
    const ushort_t* kb = kbuf + ((size_t)b*NPTS + m0 + (lane & 31))*16 + (lane >> 5)*8;

    float rs0 = 0.f, rs1 = 0.f, rs2 = 0.f, rs3 = 0.f;
    bf16x8 kf0 = *(const bf16x8*)kb;
    bf16x8 kf1 = *(const bf16x8*)(kb + 512);
    for (int t = 0; t < 16; ++t) {
        const bf16x8 kcur = kf0;
        kf0 = kf1;
        const int tn = (t + 2 < 16) ? t + 2 : 15;
        kf1 = *(const bf16x8*)(kb + (size_t)tn*512);
        f32x16 acc;
#pragma unroll
        for (int i = 0; i < 16; ++i) acc[i] = 0.f;
        acc = __builtin_amdgcn_mfma_f32_32x32x16_bf16(kcur, qfrag, acc, 0, 0, 0);
#pragma unroll
        for (int i = 0; i < 16; i += 4) {
            rs0 += EXP2(acc[i+0]);
            rs1 += EXP2(acc[i+1]);
            rs2 += EXP2(acc[i+2]);
            rs3 += EXP2(acc[i+3]);
        }
    }
    float rsum = (rs0 + rs1) + (rs2 + rs3);
    rsum += __shfl_xor(rsum, 32);
    if (lane < 32) psum[((size_t)slice*NB + b)*NPTS + n0 + lane] = rsum;
}

// ---------------- k4: column pass, fused row-reduce + LDS aux --------------
// blockIdx: b = blk>>7, slice = (blk>>5)&3, mgroup = blk&31.
// wave widx handles mtile = mgroup*4+widx; all 4 waves share one n-slice.
__global__ __launch_bounds__(256, 4) void k4_colpass(
    const ushort_t* __restrict__ qbuf, const ushort_t* __restrict__ kbuf,
    const float* __restrict__ aux, const float* __restrict__ psum,
    float* __restrict__ pcol)
{
    __shared__ float4 s_ax[1024];

    const int tid  = threadIdx.x;
    const int lane = tid & 63;
    const int widx = tid >> 6;
    const int blk  = blockIdx.x;
    const int b      = blk >> 7;
    const int slice  = (blk >> 5) & 3;
    const int mgroup = blk & 31;
    const int mtile  = mgroup*4 + widx;
    const int m0 = mtile * 32;
    const int n0 = slice * 1024;

    // stage aux window with inv folded (fused k3)
#pragma unroll
    for (int i = 0; i < 4; ++i) {
        const int nl = tid + i*256;
        const int gn = n0 + nl;
        float s = 0.f;
#pragma unroll
        for (int sl = 0; sl < RS_SLICES; ++sl)
            s += psum[((size_t)sl*NB + b)*NPTS + gn];
        const float inv = 1.0f / s;
        const float4 v = *((const float4*)aux + (size_t)b*NPTS + gn);
        s_ax[nl] = make_float4(v.x*inv, v.y*inv, v.z*inv, inv);
    }
    __syncthreads();

    const bf16x8 afrag = *(const bf16x8*)(kbuf + ((size_t)b*NPTS + m0 + (lane & 31))*16 + (lane >> 5)*8);
    const ushort_t* qb = qbuf + ((size_t)b*NPTS + n0 + (lane & 31))*16 + (lane >> 5)*8;

    float S[16], A0[16], A1[16], A2[16];
#pragma unroll
    for (int i = 0; i < 16; ++i) { S[i] = 0.f; A0[i] = 0.f; A1[i] = 0.f; A2[i] = 0.f; }

    bf16x8 qf0 = *(const bf16x8*)qb;
    bf16x8 qf1 = *(const bf16x8*)(qb + 512);
    for (int t = 0; t < 32; ++t) {
        const bf16x8 qcur = qf0;
        qf0 = qf1;
        const int tn = (t + 2 < 32) ? t + 2 : 31;
        qf1 = *(const bf16x8*)(qb + (size_t)tn*512);
        const float4 axc = s_ax[(lane & 31) + t*32];
        f32x16 acc;
#pragma unroll
        for (int i = 0; i < 16; ++i) acc[i] = 0.f;
        acc = __builtin_amdgcn_mfma_f32_32x32x16_bf16(afrag, qcur, acc, 0, 0, 0);
#pragma unroll
        for (int i = 0; i < 16; ++i) {
            const float e1 = EXP2(acc[i]);
            S[i]  = fmaf(axc.w, e1, S[i]);
            A0[i] = fmaf(axc.x, e1, A0[i]);
            A1[i] = fmaf(axc.y, e1, A1[i]);
            A2[i] = fmaf(axc.z, e1, A2[i]);
        }
    }

    // allreduce over the 32 columns (low 5 lane bits)
#pragma unroll
    for (int d = 1; d <= 16; d <<= 1) {
#pragma unroll
        for (int i = 0; i < 16; ++i) {
            S[i]  += __shfl_xor(S[i],  d);
            A0[i] += __shfl_xor(A0[i], d);
            A1[i] += __shfl_xor(A1[i], d);
            A2[i] += __shfl_xor(A2[i], d);
        }
    }

    if ((lane & 31) == 0) {
        const int hi = lane >> 5;
        float* base = pcol + (((size_t)b*CS_SLICES + slice)*4)*NPTS;
#pragma unroll
        for (int i = 0; i < 16; ++i) {
            const int m = m0 + (i & 3) + 8*(i >> 2) + 4*hi;
            base[0*NPTS + m] = S[i];
            base[1*NPTS + m] = A0[i];
            base[2*NPTS + m] = A1[i];
            base[3*NPTS + m] = A2[i];
        }
    }
}

// ---------------- k5: reduce slices + epilogue ----------------
__global__ __launch_bounds__(256) void k5_final(
    const float* __restrict__ pcol, const float* __restrict__ x,
    const float* __restrict__ alpha, float* __restrict__ out)
{
    const int p = blockIdx.x*256 + threadIdx.x;
    const int b = p >> 12;
    const int m = p & 4095;
    float s = 0.f, a0 = 0.f, a1 = 0.f, a2 = 0.f;
#pragma unroll
    for (int sl = 0; sl < CS_SLICES; ++sl) {
        const float* base = pcol + (((size_t)b*CS_SLICES + sl)*4)*NPTS;
        s  += base[0*NPTS + m];
        a0 += base[1*NPTS + m];
        a1 += base[2*NPTS + m];
        a2 += base[3*NPTS + m];
    }
    const float sc = alpha[0] / (1e-9f + s);
    const float* xb = x + (size_t)b*3*NPTS + m;
    float* ob = out + (size_t)b*3*NPTS + m;
    ob[0*NPTS] = fmaf(a0, sc, xb[0*NPTS]);
    ob[1*NPTS] = fmaf(a1, sc, xb[1*NPTS]);
    ob[2*NPTS] = fmaf(a2, sc, xb[2*NPTS]);
}

extern "C" void kernel_launch(void* const* d_in, const int* in_sizes, int n_in,
                              void* d_out, int out_size, void* d_ws, size_t ws_size,
                              hipStream_t stream) {
    const float* x      = (const float*)d_in[0];
    const float* w1     = (const float*)d_in[1];
    const float* g1     = (const float*)d_in[2];
    const float* b1     = (const float*)d_in[3];
    const float* m1     = (const float*)d_in[4];
    const float* v1     = (const float*)d_in[5];
    const float* w2     = (const float*)d_in[6];
    const float* wq     = (const float*)d_in[7];
    const float* gq     = (const float*)d_in[8];
    const float* bq     = (const float*)d_in[9];
    const float* mq     = (const float*)d_in[10];
    const float* vq     = (const float*)d_in[11];
    const float* wk     = (const float*)d_in[12];
    const float* gk     = (const float*)d_in[13];
    const float* bk     = (const float*)d_in[14];
    const float* mk     = (const float*)d_in[15];
    const float* vk     = (const float*)d_in[16];
    const float* wv     = (const float*)d_in[17];
    const float* gv     = (const float*)d_in[18];
    const float* bv     = (const float*)d_in[19];
    const float* mv     = (const float*)d_in[20];
    const float* vv     = (const float*)d_in[21];
    const float* alpha  = (const float*)d_in[22];
    const float* offset = (const float*)d_in[23];

    char* ws = (char*)d_ws;
    float*    Wc   = (float*)(ws + 0);
    float*    tb   = (float*)(ws + 16*1024);
    float*    w1s  = (float*)(ws + 32*1024);
    float*    t1   = (float*)(ws + 48*1024);
    ushort_t* qbuf = (ushort_t*)(ws + 64*1024);
    ushort_t* kbuf = (ushort_t*)(ws + 64*1024 + (size_t)1*1024*1024);
    float*    aux  = (float*)(ws + 64*1024 + (size_t)2*1024*1024);
    float*    psum = (float*)(ws + 64*1024 + (size_t)2*1024*1024 + 512*1024);
    float*    pcol = (float*)(ws + 64*1024 + (size_t)4*1024*1024);

    k0_prep<<<dim3(36), dim3(256), 0, stream>>>(
        w1, g1, b1, m1, v1, w2,
        wq, gq, bq, mq, vq,
        wk, gk, bk, mk, vk,
        wv, gv, bv, mv, vv,
        Wc, tb, w1s, t1);

    k1_mlp<<<dim3(512), dim3(256), 0, stream>>>(
        x, offset, Wc, tb, w1s, t1, qbuf, kbuf, aux);

    k2_rowsum<<<dim3(2048), dim3(256), 0, stream>>>(qbuf, kbuf, psum);
    k4_colpass<<<dim3(1024), dim3(256), 0, stream>>>(qbuf, kbuf, aux, psum, pcol);
    k5_final<<<dim3(128), dim3(256), 0, stream>>>(pcol, x, alpha, (float*)d_out);
}

// Round 14
// 166.928 us; speedup vs baseline: 1.0433x; 1.0433x over previous
//
#include <hip/hip_runtime.h>

#define NPTS 4096
#define NB   8
#define BN_EPS 1e-5f
#define LOG2E 1.4426950408889634f
#define RS_SLICES 8   // m-slices in row-sum pass (k2)
#define CS_SLICES 4   // n-slices in column pass (k4)

typedef float f32x16 __attribute__((ext_vector_type(16)));
typedef short bf16x8 __attribute__((ext_vector_type(8)));
typedef unsigned short ushort_t;

#if __has_builtin(__builtin_amdgcn_exp2f)
#define EXP2(x) __builtin_amdgcn_exp2f(x)
#else
#define EXP2(x) exp2f(x)
#endif

__device__ __forceinline__ ushort_t f2bf(float f) {
    unsigned u = __builtin_bit_cast(unsigned, f);
    unsigned r = (u + 0x7FFFu + ((u >> 16) & 1u)) >> 16;
    return (ushort_t)r;
}

// ---------------- k0: fold BN + combine head weights with w2 ----------------
__global__ __launch_bounds__(256) void k0_prep(
    const float* __restrict__ w1, const float* __restrict__ g1, const float* __restrict__ b1,
    const float* __restrict__ m1, const float* __restrict__ v1,
    const float* __restrict__ w2,
    const float* __restrict__ wq, const float* __restrict__ gq, const float* __restrict__ bq,
    const float* __restrict__ mq, const float* __restrict__ vq,
    const float* __restrict__ wk, const float* __restrict__ gk, const float* __restrict__ bk,
    const float* __restrict__ mk, const float* __restrict__ vk,
    const float* __restrict__ wv, const float* __restrict__ gv, const float* __restrict__ bv,
    const float* __restrict__ mv, const float* __restrict__ vv,
    float* __restrict__ Wc, float* __restrict__ tb,
    float* __restrict__ w1s, float* __restrict__ t1)
{
    const int j = blockIdx.x;
    const int t = threadIdx.x;
    if (j == 35) {
        if (t < 64) {
            float s = g1[t] * rsqrtf(v1[t] + BN_EPS);
            w1s[t*3+0] = s * w1[t*3+0];
            w1s[t*3+1] = s * w1[t*3+1];
            w1s[t*3+2] = s * w1[t*3+2];
            t1[t] = b1[t] - s * m1[t];
        }
        return;
    }
    __shared__ float red[256];
    const int c = t & 63;
    const int chunk = t >> 6;
    const float* wrow;
    float g, bb, mm, vr, post = 1.f;
    if (j < 16)      { wrow = wq + j*128;      g = gq[j];    bb = bq[j];    mm = mq[j];    vr = vq[j];    post = LOG2E; }
    else if (j < 32) { int u = j-16; wrow = wk + u*128; g = gk[u]; bb = bk[u]; mm = mk[u]; vr = vk[u]; }
    else             { int u = j-32; wrow = wv + u*128; g = gv[u]; bb = bv[u]; mm = mv[u]; vr = vv[u]; }
    float acc = 0.f;
    for (int o = chunk*32; o < chunk*32 + 32; ++o) acc = fmaf(wrow[o], w2[o*64 + c], acc);
    red[t] = acc;
    __syncthreads();
    if (t < 64) {
        const float s4 = red[t] + red[64+t] + red[128+t] + red[192+t];
        const float sbn = g * rsqrtf(vr + BN_EPS);
        Wc[j*64 + t] = post * sbn * s4;
        if (t == 0) tb[j] = post * (bb - sbn * mm);
    }
}

// ---------------- k1: per-point MLP -> q(bf16, xlog2e), k(bf16), v(aux f32) ----
__global__ __launch_bounds__(128) void k1_mlp(
    const float* __restrict__ x, const float* __restrict__ offset,
    const float* __restrict__ Wc, const float* __restrict__ tb,
    const float* __restrict__ w1s, const float* __restrict__ t1,
    ushort_t* __restrict__ qbuf, ushort_t* __restrict__ kbuf, float* __restrict__ aux)
{
    const int p = blockIdx.x*128 + threadIdx.x;
    const int b = p >> 12;
    const int n = p & 4095;
    const float off = offset[0];
    const float* xb = x + (size_t)b*3*NPTS + n;
    const float x0 = xb[0] + off, x1 = xb[NPTS] + off, x2 = xb[2*NPTS] + off;

    float acc[35];
#pragma unroll
    for (int j = 0; j < 35; ++j) acc[j] = tb[j];

    for (int c = 0; c < 64; ++c) {
        const float h = fmaxf(
            fmaf(w1s[c*3+0], x0, fmaf(w1s[c*3+1], x1, fmaf(w1s[c*3+2], x2, t1[c]))), 0.f);
        const float* wc = Wc + c;
#pragma unroll
        for (int j = 0; j < 35; ++j) acc[j] = fmaf(wc[j*64], h, acc[j]);
    }

    unsigned qw[8], kw[8];
#pragma unroll
    for (int i = 0; i < 8; ++i) {
        ushort_t qlo = f2bf(fmaxf(acc[2*i],    0.f));
        ushort_t qhi = f2bf(fmaxf(acc[2*i+1],  0.f));
        qw[i] = (unsigned)qlo | ((unsigned)qhi << 16);
        ushort_t klo = f2bf(fmaxf(acc[16+2*i],   0.f));
        ushort_t khi = f2bf(fmaxf(acc[16+2*i+1], 0.f));
        kw[i] = (unsigned)klo | ((unsigned)khi << 16);
    }
    uint4* qd = (uint4*)(qbuf + (size_t)p*16);
    qd[0] = make_uint4(qw[0], qw[1], qw[2], qw[3]);
    qd[1] = make_uint4(qw[4], qw[5], qw[6], qw[7]);
    uint4* kd = (uint4*)(kbuf + (size_t)p*16);
    kd[0] = make_uint4(kw[0], kw[1], kw[2], kw[3]);
    kd[1] = make_uint4(kw[4], kw[5], kw[6], kw[7]);
    float4* ar = (float4*)(aux + (size_t)p*4);
    *ar = make_float4(fmaxf(acc[32], 0.f), fmaxf(acc[33], 0.f), fmaxf(acc[34], 0.f), 0.f);
}

// ---------------- k2: row sums via 32x32x16 MFMA, 8 m-slices, prefetch-2 ----
__global__ __launch_bounds__(256, 8) void k2_rowsum(
    const ushort_t* __restrict__ qbuf, const ushort_t* __restrict__ kbuf,
    float* __restrict__ psum)
{
    const int lane = threadIdx.x & 63;
    const int w = blockIdx.x*4 + (threadIdx.x >> 6);
    const int b = w >> 10;
    const int r = w & 1023;
    const int nblk = r >> 3;
    const int slice = r & 7;
    const int n0 = nblk * 32;
    const int m0 = slice * 512;

    const bf16x8 qfrag = *(const bf16x8*)(qbuf + ((size_t)b*NPTS + n0 + (lane & 31))*16 + (lane >> 5)*8);
    const ushort_t* kb = kbuf + ((size_t)b*NPTS + m0 + (lane & 31))*16 + (lane >> 5)*8;

    float rs0 = 0.f, rs1 = 0.f, rs2 = 0.f, rs3 = 0.f;
    bf16x8 kf0 = *(const bf16x8*)kb;
    bf16x8 kf1 = *(const bf16x8*)(kb + 512);
    for (int t = 0; t < 16; ++t) {
        const bf16x8 kcur = kf0;
        kf0 = kf1;
        const int tn = (t + 2 < 16) ? t + 2 : 15;
        kf1 = *(const bf16x8*)(kb + (size_t)tn*512);
        f32x16 acc;
#pragma unroll
        for (int i = 0; i < 16; ++i) acc[i] = 0.f;
        acc = __builtin_amdgcn_mfma_f32_32x32x16_bf16(kcur, qfrag, acc, 0, 0, 0);
#pragma unroll
        for (int i = 0; i < 16; i += 4) {
            rs0 += EXP2(acc[i+0]);
            rs1 += EXP2(acc[i+1]);
            rs2 += EXP2(acc[i+2]);
            rs3 += EXP2(acc[i+3]);
        }
    }
    float rsum = (rs0 + rs1) + (rs2 + rs3);
    rsum += __shfl_xor(rsum, 32);
    if (lane < 32) psum[((size_t)slice*NB + b)*NPTS + n0 + lane] = rsum;
}

// ---------------- k3: reduce row sums -> aux = {v*inv, inv} ----------------
__global__ __launch_bounds__(256) void k3_rowred(
    const float* __restrict__ psum, float* __restrict__ aux)
{
    const int p = blockIdx.x*256 + threadIdx.x;
    const int b = p >> 12;
    const int n = p & 4095;
    float s = 0.f;
#pragma unroll
    for (int sl = 0; sl < RS_SLICES; ++sl) s += psum[((size_t)sl*NB + b)*NPTS + n];
    const float inv = 1.0f / s;
    float4* ar = (float4*)(aux + (size_t)p*4);
    float4 v = *ar;
    *ar = make_float4(v.x*inv, v.y*inv, v.z*inv, inv);
}

// ---------------- k4: column pass via 32x32x16 MFMA, prefetch-3 ------------
// wave w: b = w>>9, mtile = (w&511)>>2, slice = w&3.
// A = k[32 m rows], B = q[32 n cols]; D row=m:(i&3)+8*(i>>2)+4*(lane>>5), col=n:lane&31.
__global__ __launch_bounds__(256, 4) void k4_colpass(
    const ushort_t* __restrict__ qbuf, const ushort_t* __restrict__ kbuf,
    const float* __restrict__ aux, float* __restrict__ pcol)
{
    const int lane = threadIdx.x & 63;
    const int w = blockIdx.x*4 + (threadIdx.x >> 6);
    const int b = w >> 9;
    const int r = w & 511;
    const int mtile = r >> 2;
    const int slice = r & 3;
    const int m0 = mtile * 32;
    const int n0 = slice * 1024;

    const bf16x8 afrag = *(const bf16x8*)(kbuf + ((size_t)b*NPTS + m0 + (lane & 31))*16 + (lane >> 5)*8);
    const ushort_t* qb = qbuf + ((size_t)b*NPTS + n0 + (lane & 31))*16 + (lane >> 5)*8;
    const float4* auxp = (const float4*)aux + (size_t)b*NPTS + n0 + (lane & 31);

    float S[16], A0[16], A1[16], A2[16];
#pragma unroll
    for (int i = 0; i < 16; ++i) { S[i] = 0.f; A0[i] = 0.f; A1[i] = 0.f; A2[i] = 0.f; }

    bf16x8 qf0 = *(const bf16x8*)qb;
    bf16x8 qf1 = *(const bf16x8*)(qb + 512);
    bf16x8 qf2 = *(const bf16x8*)(qb + 1024);
    float4 ax0 = auxp[0];
    float4 ax1 = auxp[32];
    float4 ax2 = auxp[64];
    for (int t = 0; t < 32; ++t) {
        const bf16x8 qcur = qf0;
        const float4 axc = ax0;
        qf0 = qf1; qf1 = qf2;
        ax0 = ax1; ax1 = ax2;
        const int tn = (t + 3 < 32) ? t + 3 : 31;
        qf2 = *(const bf16x8*)(qb + (size_t)tn*512);
        ax2 = auxp[(size_t)tn*32];
        f32x16 acc;
#pragma unroll
        for (int i = 0; i < 16; ++i) acc[i] = 0.f;
        acc = __builtin_amdgcn_mfma_f32_32x32x16_bf16(afrag, qcur, acc, 0, 0, 0);
#pragma unroll
        for (int i = 0; i < 16; ++i) {
            const float e1 = EXP2(acc[i]);
            S[i]  = fmaf(axc.w, e1, S[i]);
            A0[i] = fmaf(axc.x, e1, A0[i]);
            A1[i] = fmaf(axc.y, e1, A1[i]);
            A2[i] = fmaf(axc.z, e1, A2[i]);
        }
    }

    // allreduce over the 32 columns (low 5 lane bits)
#pragma unroll
    for (int d = 1; d <= 16; d <<= 1) {
#pragma unroll
        for (int i = 0; i < 16; ++i) {
            S[i]  += __shfl_xor(S[i],  d);
            A0[i] += __shfl_xor(A0[i], d);
            A1[i] += __shfl_xor(A1[i], d);
            A2[i] += __shfl_xor(A2[i], d);
        }
    }

    if ((lane & 31) == 0) {
        const int hi = lane >> 5;
        float* base = pcol + (((size_t)b*CS_SLICES + slice)*4)*NPTS;
#pragma unroll
        for (int i = 0; i < 16; ++i) {
            const int m = m0 + (i & 3) + 8*(i >> 2) + 4*hi;
            base[0*NPTS + m] = S[i];
            base[1*NPTS + m] = A0[i];
            base[2*NPTS + m] = A1[i];
            base[3*NPTS + m] = A2[i];
        }
    }
}

// ---------------- k5: reduce slices + epilogue ----------------
__global__ __launch_bounds__(256) void k5_final(
    const float* __restrict__ pcol, const float* __restrict__ x,
    const float* __restrict__ alpha, float* __restrict__ out)
{
    const int p = blockIdx.x*256 + threadIdx.x;
    const int b = p >> 12;
    const int m = p & 4095;
    float s = 0.f, a0 = 0.f, a1 = 0.f, a2 = 0.f;
#pragma unroll
    for (int sl = 0; sl < CS_SLICES; ++sl) {
        const float* base = pcol + (((size_t)b*CS_SLICES + sl)*4)*NPTS;
        s  += base[0*NPTS + m];
        a0 += base[1*NPTS + m];
        a1 += base[2*NPTS + m];
        a2 += base[3*NPTS + m];
    }
    const float sc = alpha[0] / (1e-9f + s);
    const float* xb = x + (size_t)b*3*NPTS + m;
    float* ob = out + (size_t)b*3*NPTS + m;
    ob[0*NPTS] = fmaf(a0, sc, xb[0*NPTS]);
    ob[1*NPTS] = fmaf(a1, sc, xb[1*NPTS]);
    ob[2*NPTS] = fmaf(a2, sc, xb[2*NPTS]);
}

extern "C" void kernel_launch(void* const* d_in, const int* in_sizes, int n_in,
                              void* d_out, int out_size, void* d_ws, size_t ws_size,
                              hipStream_t stream) {
    const float* x      = (const float*)d_in[0];
    const float* w1     = (const float*)d_in[1];
    const float* g1     = (const float*)d_in[2];
    const float* b1     = (const float*)d_in[3];
    const float* m1     = (const float*)d_in[4];
    const float* v1     = (const float*)d_in[5];
    const float* w2     = (const float*)d_in[6];
    const float* wq     = (const float*)d_in[7];
    const float* gq     = (const float*)d_in[8];
    const float* bq     = (const float*)d_in[9];
    const float* mq     = (const float*)d_in[10];
    const float* vq     = (const float*)d_in[11];
    const float* wk     = (const float*)d_in[12];
    const float* gk     = (const float*)d_in[13];
    const float* bk     = (const float*)d_in[14];
    const float* mk     = (const float*)d_in[15];
    const float* vk     = (const float*)d_in[16];
    const float* wv     = (const float*)d_in[17];
    const float* gv     = (const float*)d_in[18];
    const float* bv     = (const float*)d_in[19];
    const float* mv     = (const float*)d_in[20];
    const float* vv     = (const float*)d_in[21];
    const float* alpha  = (const float*)d_in[22];
    const float* offset = (const float*)d_in[23];

    char* ws = (char*)d_ws;
    float*    Wc   = (float*)(ws + 0);
    float*    tb   = (float*)(ws + 16*1024);
    float*    w1s  = (float*)(ws + 32*1024);
    float*    t1   = (float*)(ws + 48*1024);
    ushort_t* qbuf = (ushort_t*)(ws + 64*1024);
    ushort_t* kbuf = (ushort_t*)(ws + 64*1024 + (size_t)1*1024*1024);
    float*    aux  = (float*)(ws + 64*1024 + (size_t)2*1024*1024);
    float*    psum = (float*)(ws + 64*1024 + (size_t)2*1024*1024 + 512*1024);
    float*    pcol = (float*)(ws + 64*1024 + (size_t)4*1024*1024);

    k0_prep<<<dim3(36), dim3(256), 0, stream>>>(
        w1, g1, b1, m1, v1, w2,
        wq, gq, bq, mq, vq,
        wk, gk, bk, mk, vk,
        wv, gv, bv, mv, vv,
        Wc, tb, w1s, t1);

    k1_mlp<<<dim3(256), dim3(128), 0, stream>>>(
        x, offset, Wc, tb, w1s, t1, qbuf, kbuf, aux);

    k2_rowsum<<<dim3(2048), dim3(256), 0, stream>>>(qbuf, kbuf, psum);
    k3_rowred<<<dim3(128), dim3(256), 0, stream>>>(psum, aux);
    k4_colpass<<<dim3(1024), dim3(256), 0, stream>>>(qbuf, kbuf, aux, pcol);
    k5_final<<<dim3(128), dim3(256), 0, stream>>>(pcol, x, alpha, (float*)d_out);
}